// Round 6
// baseline (466.339 us; speedup 1.0000x reference)
//
#include <hip/hip_runtime.h>

typedef unsigned short u16;
typedef unsigned int u32;
typedef __attribute__((ext_vector_type(8))) short bf16x8;
typedef __attribute__((ext_vector_type(4))) float f32x4;

#define NN 20000      // real nodes
#define NE 320000     // edges
#define NPAD 20032    // nodes padded to x32
#define D 64
#define R 4
#define NG 128
#define NC 16
#define NL 4
#define MROWS (NN*R)        // BN divisor (real rows only)
#define NT (NPAD/32)        // 626 tiles per run
#define NBLK2 (4*NT)        // 2504 blocks
#define EPAD 480256         // padded edge slots: <= NE + 8*NN
#define BN_EPS 1e-5f

__device__ __forceinline__ float bf2f(u16 v) {
    union { u32 u; float f; } c; c.u = ((u32)v) << 16; return c.f;
}
__device__ __forceinline__ u16 f2bf(float f) {
    union { u32 u; float f; } c; c.f = f;
    u32 u = c.u;
    return (u16)((u + 0x7fffu + ((u >> 16) & 1u)) >> 16);   // RNE
}
// swizzled u16 index into a [rows][64] bf16 LDS tile
__device__ __forceinline__ int swz(int row, int kbyte) {
    return row * 64 + (((kbyte) ^ ((row & 7) << 4)) >> 1);
}

// ---------------- setup: esrc=NN fill, deg zero, H0 = masked bf16 x ----------------
__global__ void k_setup(const float* __restrict__ x, const int* __restrict__ mask,
                        u16* __restrict__ H, int* __restrict__ esrc, int* __restrict__ deg) {
    int id = blockIdx.x * 256 + threadIdx.x;
    if (id < EPAD) esrc[id] = NN;          // dummy -> zero row
    if (id < NPAD) deg[id] = 0;
    if (id < 4 * NPAD * 16) {
        int r = id / (NPAD * 16);
        int rem = id - r * (NPAD * 16);
        int n = rem >> 4, q = rem & 15;
        ushort4 o; o.x = o.y = o.z = o.w = 0;
        if (n < NN && mask[r * NN + n] == 0) {
            float4 v = *(const float4*)(x + (size_t)n * 64 + q * 4);
            o.x = f2bf(v.x); o.y = f2bf(v.y); o.z = f2bf(v.z); o.w = f2bf(v.w);
        }
        *(ushort4*)(H + ((size_t)r * NPAD + n) * 64 + q * 4) = o;
    }
}

// ---------------- CSR build ----------------
__global__ void k_deg(const int* __restrict__ dst, int* __restrict__ deg) {
    int e = blockIdx.x * 256 + threadIdx.x;
    if (e < NE) atomicAdd(&deg[dst[e]], 1);
}

// scan of (deg+1 self) padded to x8; writes self edge into first slot
__global__ __launch_bounds__(1024) void k_scan(const int* __restrict__ deg,
                                               int* __restrict__ rowstart,
                                               int* __restrict__ cursor,
                                               int* __restrict__ esrc) {
    __shared__ int wsum[16];
    __shared__ int woff[16];
    __shared__ int carry_s, chunktot;
    const int t = threadIdx.x, lane = t & 63, wv = t >> 6;
    if (t == 0) carry_s = 0;
    __syncthreads();
    for (int base = 0; base < NPAD; base += 1024) {
        int i = base + t;
        int v = (i < NN) ? ((deg[i] + 8) & ~7) : 0;   // (deg+1self) padded to x8
        int x = v;
#pragma unroll
        for (int off = 1; off < 64; off <<= 1) {
            int y = __shfl_up(x, off);
            if (lane >= off) x += y;
        }
        if (lane == 63) wsum[wv] = x;
        __syncthreads();
        if (t < 16) {
            int s = wsum[t], sx = s;
#pragma unroll
            for (int off = 1; off < 16; off <<= 1) {
                int y = __shfl_up(sx, off);
                if (t >= off) sx += y;
            }
            woff[t] = sx - s;
            if (t == 15) chunktot = sx;
        }
        __syncthreads();
        int excl = carry_s + woff[wv] + x - v;
        if (i < NPAD) rowstart[i] = excl;
        if (i < NN) { esrc[excl] = i; cursor[i] = excl + 1; }   // self slot
        __syncthreads();
        if (t == 0) carry_s += chunktot;
        __syncthreads();
    }
    if (t == 0) rowstart[NPAD] = carry_s;
}

__global__ void k_fill(const int* __restrict__ src, const int* __restrict__ dst,
                       int* __restrict__ cursor, int* __restrict__ esrc) {
    int e = blockIdx.x * 256 + threadIdx.x;
    if (e < NE) {
        int p = atomicAdd(&cursor[dst[e]], 1);
        esrc[p] = src[e];
    }
}

// ---------------- fused gather+MFMA-GEMM1+stat partials ----------------
// block = (run r = blk&3, 32 nodes); wave owns 16 nodes; gather is pure bf16 adds.
__global__ __launch_bounds__(128) void k_fgg(const u16* __restrict__ Zin,
                                             u16* __restrict__ Y,
                                             const int* __restrict__ rowstart,
                                             const int* __restrict__ esrc,
                                             const float* __restrict__ W,
                                             const float* __restrict__ bias,
                                             float* __restrict__ part) {
    __shared__ __align__(16) u16 Xs[32 * 64];
    __shared__ __align__(16) u16 Wt[64 * 64];
    __shared__ float red[256];
    const int t = threadIdx.x, lane = t & 63, wv = t >> 6;
    const int blk = blockIdx.x;
    const int r = blk & 3;
    const int node0 = (blk >> 2) * 32;
    const u16* Zr = Zin + (size_t)r * (NPAD * 64);

    {   // stage Wt[n][k] = bf16(W[k][n]) swizzled
        int k = t >> 1, c0 = (t & 1) * 32;
        const float* Wp = W + k * 64 + c0;
#pragma unroll
        for (int j = 0; j < 8; j++) {
            float4 v = *(const float4*)(Wp + j * 4);
            Wt[swz(c0 + j * 4 + 0, k * 2)] = f2bf(v.x);
            Wt[swz(c0 + j * 4 + 1, k * 2)] = f2bf(v.y);
            Wt[swz(c0 + j * 4 + 2, k * 2)] = f2bf(v.z);
            Wt[swz(c0 + j * 4 + 3, k * 2)] = f2bf(v.w);
        }
    }
    __syncthreads();

    const int g = lane >> 4, l15 = lane & 15, cl = l15 * 4;
    const int n0w = node0 + wv * 16;

    float a0 = 0.f, a1 = 0.f, a2 = 0.f, a3 = 0.f;
    int nloc = 0;
    int kk = __builtin_amdgcn_readfirstlane(rowstart[n0w]);
    int KE = __builtin_amdgcn_readfirstlane(rowstart[n0w + 16]);
    int nend = __builtin_amdgcn_readfirstlane(rowstart[n0w + 1]);

#define FLUSH()                                                                \
    {                                                                          \
        a0 += __shfl_xor(a0, 16); a0 += __shfl_xor(a0, 32);                    \
        a1 += __shfl_xor(a1, 16); a1 += __shfl_xor(a1, 32);                    \
        a2 += __shfl_xor(a2, 16); a2 += __shfl_xor(a2, 32);                    \
        a3 += __shfl_xor(a3, 16); a3 += __shfl_xor(a3, 32);                    \
        if (g == 0) {                                                          \
            ushort4 o;                                                         \
            o.x = f2bf(a0); o.y = f2bf(a1); o.z = f2bf(a2); o.w = f2bf(a3);    \
            *(ushort4*)&Xs[swz(wv * 16 + nloc, cl * 2)] = o;                   \
        }                                                                      \
        a0 = a1 = a2 = a3 = 0.f;                                               \
        nloc++;                                                                \
    }

    // 3-stage pipeline: idx 2 chunks ahead, 2 row-loads in flight, 4 edges/chunk
    ushort4 rowCur, rowNext;
    int idxA = 0, idxB = 0;
    if (kk < KE)      { int e = esrc[kk + g];     rowCur  = *(const ushort4*)(Zr + (size_t)e * 64 + cl); }
    if (kk + 4 < KE)  { int e = esrc[kk + 4 + g]; rowNext = *(const ushort4*)(Zr + (size_t)e * 64 + cl); }
    if (kk + 8 < KE)  idxA = esrc[kk + 8 + g];
    if (kk + 12 < KE) idxB = esrc[kk + 12 + g];

    for (int kc = kk; kc < KE; kc += 4) {
        if (kc == nend) {        // node boundary (8-aligned, wave-uniform)
            FLUSH();
            nend = __builtin_amdgcn_readfirstlane(rowstart[n0w + nloc + 1]);
        }
        a0 += bf2f(rowCur.x); a1 += bf2f(rowCur.y);
        a2 += bf2f(rowCur.z); a3 += bf2f(rowCur.w);
        rowCur = rowNext;
        if (kc + 8 < KE) rowNext = *(const ushort4*)(Zr + (size_t)idxA * 64 + cl);
        idxA = idxB;
        if (kc + 16 < KE) idxB = esrc[kc + 16 + g];
    }
    while (nloc < 16) FLUSH();
#undef FLUSH

    // ---- MFMA: wave computes its 16 rows x 64 cols ----
    const int l4 = lane >> 4;
    const int arow = wv * 16 + l15;
    bf16x8 af0 = *(bf16x8*)&Xs[swz(arow, l4 * 16)];
    bf16x8 af1 = *(bf16x8*)&Xs[swz(arow, 64 + l4 * 16)];
    f32x4 acc[4];
#pragma unroll
    for (int n0 = 0; n0 < 4; n0++) {
        int n = n0 * 16 + l15;
        float bv = bias[n];
        acc[n0] = (f32x4){bv, bv, bv, bv};
        bf16x8 bf0 = *(bf16x8*)&Wt[swz(n, l4 * 16)];
        bf16x8 bf1 = *(bf16x8*)&Wt[swz(n, 64 + l4 * 16)];
        acc[n0] = __builtin_amdgcn_mfma_f32_16x16x32_bf16(af0, bf0, acc[n0], 0, 0, 0);
        acc[n0] = __builtin_amdgcn_mfma_f32_16x16x32_bf16(af1, bf1, acc[n0], 0, 0, 0);
    }

    const size_t ybase = ((size_t)r * NPAD + node0) * 64;
#pragma unroll
    for (int n0 = 0; n0 < 4; n0++) {
        int col = n0 * 16 + l15;
#pragma unroll
        for (int j = 0; j < 4; j++) {
            int lrow = wv * 16 + l4 * 4 + j;
            Y[ybase + (size_t)lrow * 64 + col] = f2bf(acc[n0][j]);
        }
    }

    // stats partials (mask pad rows)
#pragma unroll
    for (int n0 = 0; n0 < 4; n0++) {
        float s = 0.f, q = 0.f;
#pragma unroll
        for (int j = 0; j < 4; j++) {
            int node = node0 + wv * 16 + l4 * 4 + j;
            float vm = (node < NN) ? 1.f : 0.f;
            float v = vm * acc[n0][j];
            s += v; q += v * acc[n0][j];
        }
        s += __shfl_xor(s, 16); s += __shfl_xor(s, 32);
        q += __shfl_xor(q, 16); q += __shfl_xor(q, 32);
        if (l4 == 0) {
            red[wv * 128 + n0 * 16 + l15] = s;
            red[wv * 128 + 64 + n0 * 16 + l15] = q;
        }
    }
    __syncthreads();
    if (t < 128) part[(size_t)t * NBLK2 + blk] = red[t] + red[128 + t];
}

// ---------------- GEMM2: BN+ReLU staging, MFMA, stat partials ----------------
__global__ __launch_bounds__(128) void k_gemm(const u16* __restrict__ Pin,
                                              u16* __restrict__ Qout,
                                              const float* __restrict__ W,
                                              const float* __restrict__ bias,
                                              const float* __restrict__ inStats,
                                              const float* __restrict__ gamma,
                                              const float* __restrict__ beta,
                                              float* __restrict__ part) {
    __shared__ __align__(16) u16 Xs[32 * 64];
    __shared__ __align__(16) u16 Wt[64 * 64];
    __shared__ float red[256];
    __shared__ float Psc[64], Psh[64];
    const int t = threadIdx.x, lane = t & 63, wv = t >> 6;
    const int blk = blockIdx.x;
    const int r = blk & 3;
    const int node0 = (blk >> 2) * 32;

    {   // stage Wt
        int k = t >> 1, c0 = (t & 1) * 32;
        const float* Wp = W + k * 64 + c0;
#pragma unroll
        for (int j = 0; j < 8; j++) {
            float4 v = *(const float4*)(Wp + j * 4);
            Wt[swz(c0 + j * 4 + 0, k * 2)] = f2bf(v.x);
            Wt[swz(c0 + j * 4 + 1, k * 2)] = f2bf(v.y);
            Wt[swz(c0 + j * 4 + 2, k * 2)] = f2bf(v.z);
            Wt[swz(c0 + j * 4 + 3, k * 2)] = f2bf(v.w);
        }
    }
    if (t < 64) {
        float m = inStats[t] * (1.0f / MROWS);
        float var = inStats[64 + t] * (1.0f / MROWS) - m * m;
        float sc = gamma[t] * rsqrtf(var + BN_EPS);
        Psc[t] = sc;
        Psh[t] = beta[t] - m * sc;
    }
    __syncthreads();

    const int row = t >> 2, cb = (t & 3) * 16;
    const size_t base = ((size_t)r * NPAD + node0) * 64;
    {   // stage X (wave-own rows), affine+relu, bf16, swizzled
        const u16* Xp = Pin + base + (size_t)row * 64 + cb;
        uint4 a = *(const uint4*)Xp;
        uint4 bq = *(const uint4*)(Xp + 8);
        u32 w[8] = {a.x, a.y, a.z, a.w, bq.x, bq.y, bq.z, bq.w};
        u32 ow[8];
#pragma unroll
        for (int j = 0; j < 8; j++) {
            int c = cb + 2 * j;
            union { u32 u; float f; } lo, hi;
            lo.u = w[j] << 16;
            hi.u = w[j] & 0xffff0000u;
            float v0 = fmaxf(fmaf(lo.f, Psc[c], Psh[c]), 0.f);
            float v1 = fmaxf(fmaf(hi.f, Psc[c + 1], Psh[c + 1]), 0.f);
            ow[j] = (u32)f2bf(v0) | ((u32)f2bf(v1) << 16);
        }
        *(uint4*)&Xs[swz(row, cb * 2)] = make_uint4(ow[0], ow[1], ow[2], ow[3]);
        *(uint4*)&Xs[swz(row, cb * 2 + 16)] = make_uint4(ow[4], ow[5], ow[6], ow[7]);
    }

    const int l4 = lane >> 4, l15 = lane & 15;
    const int arow = wv * 16 + l15;
    bf16x8 af0 = *(bf16x8*)&Xs[swz(arow, l4 * 16)];
    bf16x8 af1 = *(bf16x8*)&Xs[swz(arow, 64 + l4 * 16)];
    f32x4 acc[4];
#pragma unroll
    for (int n0 = 0; n0 < 4; n0++) {
        int n = n0 * 16 + l15;
        float bv = bias[n];
        acc[n0] = (f32x4){bv, bv, bv, bv};
        bf16x8 bf0 = *(bf16x8*)&Wt[swz(n, l4 * 16)];
        bf16x8 bf1 = *(bf16x8*)&Wt[swz(n, 64 + l4 * 16)];
        acc[n0] = __builtin_amdgcn_mfma_f32_16x16x32_bf16(af0, bf0, acc[n0], 0, 0, 0);
        acc[n0] = __builtin_amdgcn_mfma_f32_16x16x32_bf16(af1, bf1, acc[n0], 0, 0, 0);
    }

#pragma unroll
    for (int n0 = 0; n0 < 4; n0++) {
        int col = n0 * 16 + l15;
#pragma unroll
        for (int j = 0; j < 4; j++) {
            int lrow = wv * 16 + l4 * 4 + j;
            Qout[base + (size_t)lrow * 64 + col] = f2bf(acc[n0][j]);
        }
    }

#pragma unroll
    for (int n0 = 0; n0 < 4; n0++) {
        float s = 0.f, q = 0.f;
#pragma unroll
        for (int j = 0; j < 4; j++) {
            int node = node0 + wv * 16 + l4 * 4 + j;
            float vm = (node < NN) ? 1.f : 0.f;
            float v = vm * acc[n0][j];
            s += v; q += v * acc[n0][j];
        }
        s += __shfl_xor(s, 16); s += __shfl_xor(s, 32);
        q += __shfl_xor(q, 16); q += __shfl_xor(q, 32);
        if (l4 == 0) {
            red[wv * 128 + n0 * 16 + l15] = s;
            red[wv * 128 + 64 + n0 * 16 + l15] = q;
        }
    }
    __syncthreads();
    if (t < 128) part[(size_t)t * NBLK2 + blk] = red[t] + red[128 + t];
}

// ---------------- reduce stat partials ----------------
__global__ __launch_bounds__(256) void k_statreduce(const float* __restrict__ part,
                                                    float* __restrict__ stats) {
    const int j = blockIdx.x, t = threadIdx.x;
    float s = 0.f;
    for (int p = t; p < NBLK2; p += 256) s += part[(size_t)j * NBLK2 + p];
#pragma unroll
    for (int off = 32; off > 0; off >>= 1) s += __shfl_xor(s, off);
    __shared__ float red[4];
    if ((t & 63) == 0) red[t >> 6] = s;
    __syncthreads();
    if (t == 0) stats[j] = red[0] + red[1] + red[2] + red[3];
}

// ---------------- pool (+optional BN+ReLU and H materialization) ----------------
// one block per graph; wave w handles run w.
template <bool APPLY>
__global__ __launch_bounds__(256) void k_pool(const u16* __restrict__ Zin,
                                              const int* __restrict__ batch,
                                              float* __restrict__ pooled,
                                              u16* __restrict__ Hout,
                                              const float* __restrict__ stats,
                                              const float* __restrict__ g,
                                              const float* __restrict__ b) {
    const int gr = blockIdx.x, t = threadIdx.x;
    int lo = 0, hi = NN;
    while (lo < hi) { int mid = (lo + hi) >> 1; if (batch[mid] < gr) lo = mid + 1; else hi = mid; }
    const int start = lo;
    lo = 0; hi = NN;
    while (lo < hi) { int mid = (lo + hi) >> 1; if (batch[mid] < gr + 1) lo = mid + 1; else hi = mid; }
    const int end = lo;

    const int w = t >> 6, lane = t & 63, gg = lane >> 4, l15 = lane & 15, cl = l15 * 4;
    const u16* Zr = Zin + (size_t)w * (NPAD * 64);
    u16* Hr = Hout + (size_t)w * (NPAD * 64);
    float sc[4], sh[4];
    if (APPLY) {
#pragma unroll
        for (int j = 0; j < 4; j++) {
            int c = cl + j;
            float m = stats[c] * (1.f / MROWS);
            float var = stats[64 + c] * (1.f / MROWS) - m * m;
            float s = g[c] * rsqrtf(var + BN_EPS);
            sc[j] = s;
            sh[j] = b[c] - m * s;
        }
    }
    float a0 = 0.f, a1 = 0.f, a2 = 0.f, a3 = 0.f;
    for (int n = start + gg; n < end; n += 4) {
        ushort4 v = *(const ushort4*)(Zr + (size_t)n * 64 + cl);
        float f0 = bf2f(v.x), f1 = bf2f(v.y), f2 = bf2f(v.z), f3 = bf2f(v.w);
        if (APPLY) {
            f0 = fmaxf(fmaf(f0, sc[0], sh[0]), 0.f);
            f1 = fmaxf(fmaf(f1, sc[1], sh[1]), 0.f);
            f2 = fmaxf(fmaf(f2, sc[2], sh[2]), 0.f);
            f3 = fmaxf(fmaf(f3, sc[3], sh[3]), 0.f);
            ushort4 o;
            o.x = f2bf(f0); o.y = f2bf(f1); o.z = f2bf(f2); o.w = f2bf(f3);
            *(ushort4*)(Hr + (size_t)n * 64 + cl) = o;   // next layer's gather input
        }
        a0 += f0; a1 += f1; a2 += f2; a3 += f3;
    }
    a0 += __shfl_xor(a0, 16); a0 += __shfl_xor(a0, 32);
    a1 += __shfl_xor(a1, 16); a1 += __shfl_xor(a1, 32);
    a2 += __shfl_xor(a2, 16); a2 += __shfl_xor(a2, 32);
    a3 += __shfl_xor(a3, 16); a3 += __shfl_xor(a3, 32);
    __shared__ float red[4 * 64];
    if (gg == 0) {
        red[w * 64 + cl + 0] = a0; red[w * 64 + cl + 1] = a1;
        red[w * 64 + cl + 2] = a2; red[w * 64 + cl + 3] = a3;
    }
    __syncthreads();
    if (t < 64)
        pooled[gr * 64 + t] = 0.25f * (red[t] + red[64 + t] + red[128 + t] + red[192 + t]);
}

// ---------------- readout ----------------
__global__ __launch_bounds__(256) void k_readout(const float* __restrict__ pooled,
                                                 const float* __restrict__ fcW,
                                                 const float* __restrict__ fcb,
                                                 float* __restrict__ out) {
    const int gr = blockIdx.x, t = threadIdx.x;
    const int c = t & 15, seg = t >> 4;
    float acc = 0.f;
#pragma unroll
    for (int i = 0; i < 5; i++)
#pragma unroll
        for (int k = 0; k < 4; k++) {
            int d = seg * 4 + k;
            acc = fmaf(pooled[i * (NG * D) + gr * D + d], fcW[i * 1024 + d * 16 + c], acc);
        }
    __shared__ float red[16][17];
    red[seg][c] = acc;
    __syncthreads();
    if (t < 16) {
        float s = 0.f;
#pragma unroll
        for (int s2 = 0; s2 < 16; s2++) s += red[s2][t];
#pragma unroll
        for (int i = 0; i < 5; i++) s += fcb[i * NC + t];
        float mx = s;
#pragma unroll
        for (int m = 1; m < 16; m <<= 1) mx = fmaxf(mx, __shfl_xor(mx, m));
        float e = expf(s - mx), se = e;
#pragma unroll
        for (int m = 1; m < 16; m <<= 1) se += __shfl_xor(se, m);
        out[gr * NC + t] = s - mx - logf(se);
    }
}

extern "C" void kernel_launch(void* const* d_in, const int* in_sizes, int n_in,
                              void* d_out, int out_size, void* d_ws, size_t ws_size,
                              hipStream_t stream) {
    const float* x = (const float*)d_in[0];
    const int* ei = (const int*)d_in[1];
    const int* srcp = ei;
    const int* dstp = ei + NE;
    const int* batch = (const int*)d_in[2];
    const int* mask = (const int*)d_in[3];
    const float* convW1 = (const float*)d_in[4];
    const float* convb1 = (const float*)d_in[5];
    const float* mlp_bn_g = (const float*)d_in[6];
    const float* mlp_bn_b = (const float*)d_in[7];
    const float* convW2 = (const float*)d_in[8];
    const float* convb2 = (const float*)d_in[9];
    const float* bn_g = (const float*)d_in[10];
    const float* bn_b = (const float*)d_in[11];
    const float* fcW = (const float*)d_in[12];
    const float* fcb = (const float*)d_in[13];
    float* out = (float*)d_out;

    u16* H = (u16*)d_ws;                       // [4][NPAD][64] bf16 = 10.26 MB
    u16* P = H + (size_t)4 * NPAD * 64;
    u16* Q = P + (size_t)4 * NPAD * 64;
    float* pooled = (float*)(Q + (size_t)4 * NPAD * 64);   // [5][NG][64]
    float* stats = pooled + 5 * NG * D;        // [NL][2][128]
    float* part = stats + NL * 2 * 128;        // [128][NBLK2]
    int* rowstart = (int*)(part + 128 * NBLK2);  // [NPAD+1]
    int* cursor = rowstart + NPAD + 1;           // [NN]
    int* deg = cursor + NPAD;                    // [NPAD]
    int* esrc = deg + NPAD;                      // [EPAD]

    k_setup<<<(4 * NPAD * 16) / 256, 256, 0, stream>>>(x, mask, H, esrc, deg);
    k_deg<<<(NE + 255) / 256, 256, 0, stream>>>(dstp, deg);
    k_scan<<<1, 1024, 0, stream>>>(deg, rowstart, cursor, esrc);
    k_fill<<<(NE + 255) / 256, 256, 0, stream>>>(srcp, dstp, cursor, esrc);

    k_pool<false><<<NG, 256, 0, stream>>>(H, batch, pooled, P /*unused*/,
                                          nullptr, nullptr, nullptr);

    for (int i = 0; i < NL; i++) {
        float* st1 = stats + (i * 2 + 0) * 128;
        float* st2 = stats + (i * 2 + 1) * 128;
        k_fgg<<<NBLK2, 128, 0, stream>>>(H, P, rowstart, esrc,
                                         convW1 + i * 4096, convb1 + i * 64, part);
        k_statreduce<<<128, 256, 0, stream>>>(part, st1);
        k_gemm<<<NBLK2, 128, 0, stream>>>(P, Q, convW2 + i * 4096, convb2 + i * 64,
                                          st1, mlp_bn_g + i * 64, mlp_bn_b + i * 64, part);
        k_statreduce<<<128, 256, 0, stream>>>(part, st2);
        k_pool<true><<<NG, 256, 0, stream>>>(Q, batch, pooled + (i + 1) * (NG * D), H,
                                             st2, bn_g + i * 64, bn_b + i * 64);
    }

    k_readout<<<NG, 256, 0, stream>>>(pooled, fcW, fcb, out);
}